// Round 1
// baseline (89.813 us; speedup 1.0000x reference)
//
#include <hip/hip_runtime.h>

#define BINS 10

// ---------------------------------------------------------------------------
// GHM loss, single fused pass.
//   out = (1/tot) * sum_b bin_w[b] * bceSum[b]
// where bin_w depends only on per-bin counts + acc_sum (10 values).
// Pass 1: per-bin {count, bce-sum} histogram (registers -> wave shuffle ->
//         block LDS -> global atomics into d_ws).
// Pass 2: trivial finalize on 10 bins.
// ---------------------------------------------------------------------------

__device__ __forceinline__ float wave_reduce_add(float v) {
#pragma unroll
    for (int off = 32; off > 0; off >>= 1) v += __shfl_down(v, off, 64);
    return v;
}

__global__ __launch_bounds__(256) void ghm_pass1(
    const float* __restrict__ pred, const int* __restrict__ target,
    float* __restrict__ g_sum,          // [BINS] bce sums
    unsigned int* __restrict__ g_cnt,   // [BINS] counts
    int n4, int n)
{
    float sumf[BINS];
    float cntf[BINS];
#pragma unroll
    for (int b = 0; b < BINS; ++b) { sumf[b] = 0.f; cntf[b] = 0.f; }

    const float4* __restrict__ p4 = reinterpret_cast<const float4*>(pred);
    const int4*   __restrict__ t4 = reinterpret_cast<const int4*>(target);

    const int tid    = blockIdx.x * blockDim.x + threadIdx.x;
    const int stride = gridDim.x * blockDim.x;

    for (int i = tid; i < n4; i += stride) {
        const float4 xv = p4[i];
        const int4   tv = t4[i];
        const float xs[4] = {xv.x, xv.y, xv.z, xv.w};
        const int   ts[4] = {tv.x, tv.y, tv.z, tv.w};
#pragma unroll
        for (int j = 0; j < 4; ++j) {
            const float x    = xs[j];
            const bool  tpos = (ts[j] != 0);
            // E = exp(-|x|) in (0,1];  sigmoid + BCE tail both derive from it.
            const float E   = __expf(-fabsf(x));
            const float r   = 1.0f + E;
            const float inv = __builtin_amdgcn_rcpf(r);   // ~1ulp rcp
            // g = |sigmoid(x) - t| without materializing sigmoid:
            //   (x>=0)==(t==1)  ->  E/(1+E)   else  1/(1+E)
            const bool  cond = ((x >= 0.0f) == tpos);
            const float g    = cond ? (E * inv) : inv;
            // bce = max(x,0) - x*t + log(1+exp(-|x|))
            const float bce = fmaxf(x, 0.0f) - (tpos ? x : 0.0f) + __logf(r);

            // Bin predicate matches searchsorted(border, g, 'right')-1 clipped:
            // bin b  <=>  g >= b/10  &&  g < (b+1)/10  (edges handled: g in [0,1])
#pragma unroll
            for (int b = 0; b < BINS; ++b) {
                const bool lo = (b == 0)        ? true : (g >= (float)b / (float)BINS);
                const bool hi = (b == BINS - 1) ? true : (g <  (float)(b + 1) / (float)BINS);
                const float w = (lo && hi) ? 1.0f : 0.0f;
                cntf[b] += w;                                  // <=64/thread: exact
                sumf[b] = __builtin_fmaf(w, bce, sumf[b]);
            }
        }
    }

    // Scalar tail (N % 4), done by one thread before reduction (N=2^25 -> none).
    if (tid == 0) {
        for (int i = n4 * 4; i < n; ++i) {
            const float x    = pred[i];
            const bool  tpos = (target[i] != 0);
            const float E   = __expf(-fabsf(x));
            const float r   = 1.0f + E;
            const float inv = __builtin_amdgcn_rcpf(r);
            const bool  cond = ((x >= 0.0f) == tpos);
            const float g    = cond ? (E * inv) : inv;
            const float bce = fmaxf(x, 0.0f) - (tpos ? x : 0.0f) + __logf(r);
#pragma unroll
            for (int b = 0; b < BINS; ++b) {
                const bool lo = (b == 0)        ? true : (g >= (float)b / (float)BINS);
                const bool hi = (b == BINS - 1) ? true : (g <  (float)(b + 1) / (float)BINS);
                if (lo && hi) { cntf[b] += 1.0f; sumf[b] += bce; }
            }
        }
    }

    // wave -> block -> global reduction
    __shared__ float s_sum[BINS];
    __shared__ float s_cnt[BINS];
    if (threadIdx.x < BINS) { s_sum[threadIdx.x] = 0.f; s_cnt[threadIdx.x] = 0.f; }
    __syncthreads();

    const int lane = threadIdx.x & 63;
#pragma unroll
    for (int b = 0; b < BINS; ++b) {
        const float v = wave_reduce_add(sumf[b]);
        const float c = wave_reduce_add(cntf[b]);
        if (lane == 0) { atomicAdd(&s_sum[b], v); atomicAdd(&s_cnt[b], c); }
    }
    __syncthreads();

    if (threadIdx.x < BINS) {
        atomicAdd(&g_sum[threadIdx.x], s_sum[threadIdx.x]);
        // block partial count <= 16384 -> exact in float; convert exactly.
        atomicAdd(&g_cnt[threadIdx.x], (unsigned int)(s_cnt[threadIdx.x] + 0.5f));
    }
}

__global__ void ghm_finalize(const float* __restrict__ g_sum,
                             const unsigned int* __restrict__ g_cnt,
                             const float* __restrict__ acc_sum,
                             float* __restrict__ out, float tot)
{
    if (threadIdx.x == 0 && blockIdx.x == 0) {
        float binw[BINS];
        int n = 0;
#pragma unroll
        for (int b = 0; b < BINS; ++b) {
            const float c  = (float)g_cnt[b];
            const bool  ne = (c > 0.0f);
            const float accn = ne ? (0.9f * acc_sum[b] + 0.1f * c) : acc_sum[b];
            binw[b] = ne ? (tot / accn) : 0.0f;
            n += ne ? 1 : 0;
        }
        const float scale = (n > 0) ? (1.0f / (float)n) : 1.0f;  // /max(n,1) if n>0
        float res = 0.0f;
#pragma unroll
        for (int b = 0; b < BINS; ++b) res += (binw[b] * scale) * g_sum[b];
        out[0] = res / tot;
    }
}

extern "C" void kernel_launch(void* const* d_in, const int* in_sizes, int n_in,
                              void* d_out, int out_size, void* d_ws, size_t ws_size,
                              hipStream_t stream) {
    const float* pred    = (const float*)d_in[0];
    const int*   target  = (const int*)d_in[1];
    const float* acc_sum = (const float*)d_in[2];
    float*       out     = (float*)d_out;

    const int n  = in_sizes[0];
    const int n4 = n / 4;

    float*        g_sum = (float*)d_ws;
    unsigned int* g_cnt = (unsigned int*)((float*)d_ws + BINS);

    // Accumulators must be zeroed every call (ws is poisoned once, not re-poisoned).
    hipMemsetAsync(d_ws, 0, 2 * BINS * sizeof(float), stream);

    ghm_pass1<<<2048, 256, 0, stream>>>(pred, target, g_sum, g_cnt, n4, n);

    const float tot = (float)(n > 1 ? n : 1);
    ghm_finalize<<<1, 64, 0, stream>>>(g_sum, g_cnt, acc_sum, out, tot);
}